// Round 15
// baseline (558.032 us; speedup 1.0000x reference)
//
#include <hip/hip_runtime.h>

#define CC   64
#define SHOT 16
#define DD   320
#define ND   1008            // (CC-1)*SHOT
#define MS   (CC * SHOT)     // 1024
#define MD   (CC * ND)       // 64512
#define MT   (MD + MS)       // 65536 = 512*128
#define LN_EPS 1e-5f

typedef __attribute__((ext_vector_type(8)))  short short8;    // 8 bf16 = 4 VGPR
typedef __attribute__((ext_vector_type(4)))  float floatx4;
typedef __attribute__((ext_vector_type(4)))  int i32x4;

__device__ __forceinline__ unsigned short f2b(float f) {     // fp32 -> bf16 RNE
  union { float f; unsigned int u; } v; v.f = f;
  unsigned int r = v.u + 0x7FFFu + ((v.u >> 16) & 1u);
  return (unsigned short)(r >> 16);
}
__device__ __forceinline__ float b2f(unsigned short b) {
  union { unsigned int u; float f; } v; v.u = ((unsigned int)b) << 16; return v.f;
}
__device__ __forceinline__ unsigned int pk2(float a, float b) {
  return (unsigned int)f2b(a) | ((unsigned int)f2b(b) << 16);
}
__device__ __forceinline__ void gl_lds16(const void* g, void* l) {
  __builtin_amdgcn_global_load_lds(
      (const __attribute__((address_space(1))) unsigned int*)g,
      (__attribute__((address_space(3))) unsigned int*)l, 16, 0, 0);
}
__device__ __forceinline__ floatx4 mfma16(short8 a, short8 b, floatx4 c) {
  return __builtin_amdgcn_mfma_f32_16x16x32_bf16(a, b, c, 0, 0, 0);
}
#define BARRIER_VM()  do { asm volatile("s_waitcnt vmcnt(0) lgkmcnt(0)" ::: "memory"); \
                           __builtin_amdgcn_s_barrier(); \
                           __builtin_amdgcn_sched_barrier(0); } while (0)

// ---------------------------------------------------------------------------
// Fused P+Qg build over merged rows [0,65536): rows <MD diff, >=MD same.
// BM=128 BN=64 BK=64, 4 waves. One pass over the gathered fp32 A-tile feeds
// TWO B-panels: W (-> P) and W*G folded (-> Qg).
//   P  = D@W  + b  - xmean[c]        Qg = D@(W G) + bg - Mg[c]
// Also fused transposed P write (PtD/PtS) via LDS bounce.
// LDS 64KB: As 2x16K | BsW 2x8K | BsG 2x8K  -> 2 blocks/CU.
// ---------------------------------------------------------------------------
__global__ __launch_bounds__(256, 2) void gemm_pqg(
    const float* __restrict__ Xg, const float* __restrict__ Xmean,
    const unsigned short* __restrict__ BtD, const unsigned short* __restrict__ BtS,
    const unsigned short* __restrict__ BtDG, const unsigned short* __restrict__ BtSG,
    const float* __restrict__ bdiff, const float* __restrict__ bsame,
    const float* __restrict__ bqg, const float* __restrict__ bsg,
    const float* __restrict__ Mg,
    unsigned short* __restrict__ P_b, unsigned short* __restrict__ Qg_b,
    unsigned short* __restrict__ PtD, unsigned short* __restrict__ PtS)
{
  __shared__ __align__(16) char smem[65536];
  const int t  = threadIdx.x;
  const int m0 = blockIdx.x * 128;
  const int n0 = blockIdx.y * 64;
  const int wid = t >> 6, lane = t & 63;
  const int wm = wid >> 1, wn = wid & 1;
  const int l15 = lane & 15, lg = lane >> 4;

  const bool isDiff = (m0 < MD);
  const unsigned short* BtW  = isDiff ? BtD  : BtS;
  const unsigned short* BtG2 = isDiff ? BtDG : BtSG;
  const float* biasW = isDiff ? bdiff : bsame;
  const float* biasG = isDiff ? bqg   : bsg;

  const int ra = t >> 1, kh = t & 1;
  const float* aptr; const float* mptr; float sa;
  {
    const int am = m0 + ra;
    if (isDiff) {
      const int c = am / ND, j = am - c * ND;
      const int oi = j >> 4, s = j & 15;
      const int oc = (oi < c) ? oi : oi + 1;
      aptr = Xg + (size_t)(oc * SHOT + s) * DD;
      mptr = Xmean + (size_t)c * DD;
      sa = -1.f;
    } else {
      const int ls = am - MD;
      aptr = Xg + (size_t)ls * DD;
      mptr = Xmean + (size_t)(ls >> 4) * DD;
      sa = 1.f;
    }
  }

  floatx4 accP[4][2], accQ[4][2];
  #pragma unroll
  for (int i = 0; i < 4; ++i)
    #pragma unroll
    for (int j = 0; j < 2; ++j) {
      accP[i][j] = (floatx4){0.f, 0.f, 0.f, 0.f};
      accQ[i][j] = (floatx4){0.f, 0.f, 0.f, 0.f};
    }

  auto stage = [&](int ks, int bufi) {
    const int k0 = ks * 64;
    char* BsW = smem + 32768 + bufi * 8192;
    char* BsG = smem + 49152 + bufi * 8192;
    #pragma unroll
    for (int it = 0; it < 2; ++it) {               // two 64x64 B tiles
      const int L = it * 256 + t;
      const int r = L >> 3, cs = L & 7;
      const int cl = cs ^ (r & 7);
      gl_lds16(BtW  + (size_t)(n0 + r) * DD + k0 + cl * 8, BsW + L * 16);
      gl_lds16(BtG2 + (size_t)(n0 + r) * DD + k0 + cl * 8, BsG + L * 16);
    }
    char* AsB = smem + bufi * 16384;
    const int kb2 = k0 + kh * 32;                  // fp32 gather+sub+cvt
    #pragma unroll
    for (int i = 0; i < 4; ++i) {
      const float4 x0  = *(const float4*)(aptr + kb2 + i * 8);
      const float4 x1  = *(const float4*)(aptr + kb2 + i * 8 + 4);
      const float4 mv0 = *(const float4*)(mptr + kb2 + i * 8);
      const float4 mv1 = *(const float4*)(mptr + kb2 + i * 8 + 4);
      i32x4 w;
      w[0] = (int)pk2(sa * (x0.x - mv0.x), sa * (x0.y - mv0.y));
      w[1] = (int)pk2(sa * (x0.z - mv0.z), sa * (x0.w - mv0.w));
      w[2] = (int)pk2(sa * (x1.x - mv1.x), sa * (x1.y - mv1.y));
      w[3] = (int)pk2(sa * (x1.z - mv1.z), sa * (x1.w - mv1.w));
      const int c  = kh * 4 + i;
      const int cw = c ^ (ra & 7);
      *(i32x4*)(AsB + ra * 128 + cw * 16) = w;
    }
  };

  auto compute = [&](int bufi) {
    const char* AsB = smem + bufi * 16384;
    const char* BsW = smem + 32768 + bufi * 8192;
    const char* BsG = smem + 49152 + bufi * 8192;
    #pragma unroll
    for (int kc = 0; kc < 2; ++kc) {
      short8 af[4], bw[2], bg[2];
      #pragma unroll
      for (int mt = 0; mt < 4; ++mt) {
        const int row = wm * 64 + mt * 16 + l15;
        const int cs  = (kc * 4 + lg) ^ (row & 7);
        af[mt] = *(const short8*)(AsB + row * 128 + cs * 16);
      }
      #pragma unroll
      for (int nt = 0; nt < 2; ++nt) {
        const int row = wn * 32 + nt * 16 + l15;
        const int cs  = (kc * 4 + lg) ^ (row & 7);
        bw[nt] = *(const short8*)(BsW + row * 128 + cs * 16);
        bg[nt] = *(const short8*)(BsG + row * 128 + cs * 16);
      }
      #pragma unroll
      for (int mt = 0; mt < 4; ++mt)
        #pragma unroll
        for (int nt = 0; nt < 2; ++nt) {
          accP[mt][nt] = mfma16(af[mt], bw[nt], accP[mt][nt]);
          accQ[mt][nt] = mfma16(af[mt], bg[nt], accQ[mt][nt]);
        }
    }
  };

  stage(0, 0);
  BARRIER_VM();
  for (int ks = 0; ks < 5; ++ks) {
    if (ks + 1 < 5) stage(ks + 1, (ks + 1) & 1);
    compute(ks & 1);
    BARRIER_VM();
  }

  // epilogue: C[row=(lane>>4)*4+r][col=lane&15]
  unsigned short* Ls = (unsigned short*)smem;      // bounce [64 n][136 m]
  #pragma unroll
  for (int nt = 0; nt < 2; ++nt) {
    const int n = n0 + wn * 32 + nt * 16 + l15;
    const float bbW = biasW[n];
    const float bbG = biasG[n];
    #pragma unroll
    for (int mt = 0; mt < 4; ++mt) {
      #pragma unroll
      for (int r = 0; r < 4; ++r) {
        const int m = m0 + wm * 64 + mt * 16 + lg * 4 + r;
        const int cm = isDiff ? (m / ND) : ((m - MD) >> 4);
        const float vP = accP[mt][nt][r] + bbW - Xmean[(size_t)cm * DD + n];
        const float vQ = accQ[mt][nt][r] + bbG - Mg[(size_t)cm * DD + n];
        const unsigned short bv16 = f2b(vP);
        P_b[(size_t)m * DD + n]  = bv16;
        Qg_b[(size_t)m * DD + n] = f2b(vQ);
        const int nl = wn * 32 + nt * 16 + l15;
        const int ml = wm * 64 + mt * 16 + lg * 4 + r;
        Ls[nl * 136 + ml] = bv16;
      }
    }
  }
  __syncthreads();
  #pragma unroll
  for (int it = 0; it < 4; ++it) {                 // fused transposed P write
    const int flat = it * 256 + t;
    const int nl = flat >> 4, ml = (flat & 15) * 8;
    const int mg = m0 + ml;
    if (isDiff) {
      const int c0c = mg / ND, c1c = (mg + 7) / ND;
      if (c0c == c1c) {
        const i32x4 v = *(const i32x4*)&Ls[nl * 136 + ml];
        *(i32x4*)&PtD[((size_t)c0c * DD + n0 + nl) * 1024 + (mg - c0c * ND)] = v;
      } else {
        #pragma unroll
        for (int j = 0; j < 8; ++j) {
          const int mj = mg + j;
          const int cj = mj / ND;
          PtD[((size_t)cj * DD + n0 + nl) * 1024 + (mj - cj * ND)] = Ls[nl * 136 + ml + j];
        }
      }
    } else {
      const int ls0 = mg - MD;
      const int cj = ls0 >> 4;
      const i32x4 v = *(const i32x4*)&Ls[nl * 136 + ml];
      *(i32x4*)&PtS[((size_t)cj * DD + n0 + nl) * 32 + (ls0 & 15)] = v;
    }
  }
}

// ---------------------------------------------------------------------------
// FC GEMM with virtual-F epilogue. BM=128 BN=160 BK=64 (grid.y=2).
// F = O@(WvWfc) + bvf + P (never stored). Per-row partials over this wave's
// 80-col slice -> part[m][slot][3], slot = blockIdx.y*2 + wn (4 slots = 320c).
// ---------------------------------------------------------------------------
__global__ __launch_bounds__(256, 2) void gemm_fc(
    const unsigned short* __restrict__ A,
    const unsigned short* __restrict__ Bt,
    const float* __restrict__ bvf,
    const unsigned short* __restrict__ ResB,
    const float* __restrict__ u,
    float* __restrict__ part)
{
  __shared__ __align__(16) char smem[73728];     // As 2x16384 | Bs 2x20480
  const int t  = threadIdx.x;
  const int m0 = blockIdx.x * 128;
  const int n0 = blockIdx.y * 160;
  const int wid = t >> 6, lane = t & 63;
  const int wm = wid >> 1, wn = wid & 1;
  const int l15 = lane & 15, lg = lane >> 4;

  floatx4 acc[4][5];
  #pragma unroll
  for (int i = 0; i < 4; ++i)
    #pragma unroll
    for (int j = 0; j < 5; ++j) acc[i][j] = (floatx4){0.f, 0.f, 0.f, 0.f};

  auto stage = [&](int ks, int bufi) {
    const int k0 = ks * 64;
    char* BsB = smem + 32768 + bufi * 20480;
    #pragma unroll
    for (int it = 0; it < 5; ++it) {               // B tile 160x64
      const int L = it * 256 + t;
      const int r = L >> 3, cs = L & 7;
      const int cl = cs ^ (r & 7);
      gl_lds16(Bt + (size_t)(n0 + r) * DD + k0 + cl * 8, BsB + L * 16);
    }
    char* AsB = smem + bufi * 16384;
    #pragma unroll
    for (int it = 0; it < 4; ++it) {               // A tile 128x64
      const int L = it * 256 + t;
      const int r = L >> 3, cs = L & 7;
      const int cl = cs ^ (r & 7);
      gl_lds16(A + (size_t)(m0 + r) * DD + k0 + cl * 8, AsB + L * 16);
    }
  };

  auto compute = [&](int bufi) {
    const char* AsB = smem + bufi * 16384;
    const char* BsB = smem + 32768 + bufi * 20480;
    #pragma unroll
    for (int kc = 0; kc < 2; ++kc) {
      short8 af[4], bf[5];
      #pragma unroll
      for (int mt = 0; mt < 4; ++mt) {
        const int row = wm * 64 + mt * 16 + l15;
        const int cs  = (kc * 4 + lg) ^ (row & 7);
        af[mt] = *(const short8*)(AsB + row * 128 + cs * 16);
      }
      #pragma unroll
      for (int nt = 0; nt < 5; ++nt) {
        const int row = wn * 80 + nt * 16 + l15;
        const int cs  = (kc * 4 + lg) ^ (row & 7);
        bf[nt] = *(const short8*)(BsB + row * 128 + cs * 16);
      }
      #pragma unroll
      for (int mt = 0; mt < 4; ++mt)
        #pragma unroll
        for (int nt = 0; nt < 5; ++nt)
          acc[mt][nt] = mfma16(af[mt], bf[nt], acc[mt][nt]);
    }
  };

  stage(0, 0);
  BARRIER_VM();
  for (int ks = 0; ks < 5; ++ks) {
    if (ks + 1 < 5) stage(ks + 1, (ks + 1) & 1);
    compute(ks & 1);
    BARRIER_VM();
  }

  // virtual-F epilogue: partial {sum F, sum F^2, sum u*F} per row, 80-col slice
  const int slot = blockIdx.y * 2 + wn;
  #pragma unroll
  for (int mt = 0; mt < 4; ++mt) {
    float ps0[4] = {0.f,0.f,0.f,0.f}, ps1[4] = {0.f,0.f,0.f,0.f}, ps2[4] = {0.f,0.f,0.f,0.f};
    #pragma unroll
    for (int nt = 0; nt < 5; ++nt) {
      const int n = n0 + wn * 80 + nt * 16 + l15;
      const float bb = bvf[n];
      const float un = u[n];
      #pragma unroll
      for (int r = 0; r < 4; ++r) {
        const int m = m0 + wm * 64 + mt * 16 + lg * 4 + r;
        const float v = acc[mt][nt][r] + bb + b2f(ResB[(size_t)m * DD + n]);
        ps0[r] += v; ps1[r] += v * v; ps2[r] += un * v;
      }
    }
    #pragma unroll
    for (int r = 0; r < 4; ++r) {
      #pragma unroll
      for (int mk = 1; mk < 16; mk <<= 1) {
        ps0[r] += __shfl_xor(ps0[r], mk);
        ps1[r] += __shfl_xor(ps1[r], mk);
        ps2[r] += __shfl_xor(ps2[r], mk);
      }
      if (l15 == 0) {
        const int m = m0 + wm * 64 + mt * 16 + lg * 4 + r;
        float* pp = part + ((size_t)m * 4 + slot) * 3;
        pp[0] = ps0[r]; pp[1] = ps1[r]; pp[2] = ps2[r];
      }
    }
  }
}

// ---------------------------------------------------------------------------
// 16x16 MFMA flash attention, merged regions (unchanged from round 14).
// ---------------------------------------------------------------------------
__global__ __launch_bounds__(256, 2) void attn16(
    const unsigned short* __restrict__ Qall, const unsigned short* __restrict__ Pall,
    const unsigned short* __restrict__ PtD, const unsigned short* __restrict__ PtS,
    unsigned short* __restrict__ Oall)
{
  __shared__ __align__(16) char smem[40960];      // staging 40960 | epi 4x10240
  const int t = threadIdx.x;
  const int wid = t >> 6, lane = t & 63;
  const int l15 = lane & 15, lg = lane >> 4;

  int bx = blockIdx.x;
  const unsigned short *Qg, *Pk, *Pt; unsigned short* Ob;
  int cls, blkq, qRows, kPitch, vtPitch, nKT, validKV, qTiles;
  if (bx < 1024) {
    bx = (bx & 7) * 128 + (bx >> 3);              // chunk 128: classes 8x..8x+7 per XCD
    cls = bx >> 4; blkq = bx & 15;
    Qg = Qall; Pk = Pall; Pt = PtD; Ob = Oall;
    qRows = ND; kPitch = ND; vtPitch = 1024; nKT = 32; validKV = ND; qTiles = 63;
  } else {
    cls = bx - 1024; blkq = 0;
    Qg = Qall + (size_t)MD * DD; Pk = Pall + (size_t)MD * DD;
    Pt = PtS; Ob = Oall + (size_t)MD * DD;
    qRows = 16; kPitch = 16; vtPitch = 32; nKT = 1; validKV = 16; qTiles = 1;
  }
  const int qt0 = blkq * 4 + wid;
  const bool wValid = qt0 < qTiles;
  const int qt = wValid ? qt0 : qTiles - 1;

  short8 qf[10];
  {
    const unsigned short* qrow = Qg + ((size_t)cls * qRows + qt * 16 + l15) * DD;
    #pragma unroll
    for (int kc = 0; kc < 10; ++kc) qf[kc] = *(const short8*)(qrow + kc * 32 + lg * 8);
  }

  floatx4 o[20];
  #pragma unroll
  for (int i = 0; i < 20; ++i) o[i] = (floatx4){0.f, 0.f, 0.f, 0.f};
  float mrun = -1e30f, lsum = 0.f;
  const float scale = 0.05590169943749474f;       // 1/sqrt(320)

  for (int kt = 0; kt < nKT; ++kt) {
    __syncthreads();
    #pragma unroll
    for (int it = 0; it < 5; ++it) {
      const int L = it * 256 + t;                 // 16B chunk
      const int r = L / 40, c = L - (L / 40) * 40;
      const int cl = (c & ~7) | ((c & 7) ^ (r & 7));
      gl_lds16(Pk + ((size_t)cls * kPitch + kt * 32 + r) * DD + cl * 8, smem + L * 16);
    }
    #pragma unroll
    for (int it = 0; it < 5; ++it) {
      const int L = it * 256 + t;
      const int d = L >> 2, c = L & 3;
      const int cl = c ^ ((d >> 1) & 3);
      gl_lds16(Pt + ((size_t)cls * DD + d) * vtPitch + kt * 32 + cl * 8,
               smem + 20480 + L * 16);
    }
    __syncthreads();

    floatx4 st0 = (floatx4){0.f,0.f,0.f,0.f}, st1 = (floatx4){0.f,0.f,0.f,0.f};
    __builtin_amdgcn_s_setprio(1);
    #pragma unroll
    for (int kc = 0; kc < 10; ++kc) {
      const int c = kc * 4 + lg;
      const int cl = (c & ~7) | ((c & 7) ^ (l15 & 7));
      const short8 k0f = *(const short8*)(smem + l15 * 640 + cl * 16);
      const short8 k1f = *(const short8*)(smem + (16 + l15) * 640 + cl * 16);
      st0 = mfma16(k0f, qf[kc], st0);
      st1 = mfma16(k1f, qf[kc], st1);
    }
    __builtin_amdgcn_s_setprio(0);

    float s[8];
    #pragma unroll
    for (int r = 0; r < 4; ++r) { s[r] = st0[r] * scale; s[4 + r] = st1[r] * scale; }
    const int kvb = kt * 32 + lg * 4;
    #pragma unroll
    for (int r = 0; r < 4; ++r) {
      if (kvb + r      >= validKV) s[r]     = -1e30f;
      if (kvb + 16 + r >= validKV) s[4 + r] = -1e30f;
    }
    float mt_ = s[0];
    #pragma unroll
    for (int i = 1; i < 8; ++i) mt_ = fmaxf(mt_, s[i]);
    mt_ = fmaxf(mt_, __shfl_xor(mt_, 16));
    mt_ = fmaxf(mt_, __shfl_xor(mt_, 32));
    if (!__all(mt_ - mrun <= 8.0f)) {             // T13 defer-max (THR=8)
      const float newm = fmaxf(mrun, mt_);
      const float alpha = __expf(mrun - newm);
      lsum *= alpha;
      #pragma unroll
      for (int i = 0; i < 20; ++i) {
        o[i][0] *= alpha; o[i][1] *= alpha; o[i][2] *= alpha; o[i][3] *= alpha;
      }
      mrun = newm;
    }
    float p[8]; float rs = 0.f;
    #pragma unroll
    for (int i = 0; i < 8; ++i) { p[i] = __expf(s[i] - mrun); rs += p[i]; }
    rs += __shfl_xor(rs, 16);
    rs += __shfl_xor(rs, 32);
    lsum += rs;

    const unsigned int pk00 = pk2(p[0], p[1]), pk01 = pk2(p[2], p[3]);
    const unsigned int pk10 = pk2(p[4], p[5]), pk11 = pk2(p[6], p[7]);
    const int src0 = l15 + ((lane >> 4) & 1) * 32;
    const int src1 = src0 + 16;
    const int y0 = __shfl((int)pk00, src0), y1 = __shfl((int)pk01, src0);
    const int y2 = __shfl((int)pk00, src1), y3 = __shfl((int)pk01, src1);
    const int z0 = __shfl((int)pk10, src0), z1 = __shfl((int)pk11, src0);
    const int z2 = __shfl((int)pk10, src1), z3 = __shfl((int)pk11, src1);
    const bool hi = lane >= 32;                   // subtile select (kv>=16)
    union { i32x4 w; short8 v; } pf;
    pf.w[0] = hi ? z0 : y0; pf.w[1] = hi ? z1 : y1;
    pf.w[2] = hi ? z2 : y2; pf.w[3] = hi ? z3 : y3;

    const int vswz = (l15 >> 1) & 3;
    __builtin_amdgcn_s_setprio(1);
    #pragma unroll
    for (int dt = 0; dt < 20; ++dt) {
      const int d = dt * 16 + l15;
      const short8 a = *(const short8*)(smem + 20480 + d * 64 + ((lg ^ vswz) << 4));
      o[dt] = mfma16(a, pf.v, o[dt]);
    }
    __builtin_amdgcn_s_setprio(0);
  }

  const float invl = 1.f / lsum;
  __syncthreads();
  char* ep = smem + wid * 10240;
  const int qx = (l15 & 7) << 4;
  #pragma unroll
  for (int dt = 0; dt < 20; ++dt) {
    const unsigned int w0 = pk2(o[dt][0] * invl, o[dt][1] * invl);
    const unsigned int w1 = pk2(o[dt][2] * invl, o[dt][3] * invl);
    *(unsigned int*)(ep + l15 * 640 + (((dt * 16 + lg * 4) * 2) ^ qx))     = w0;
    *(unsigned int*)(ep + l15 * 640 + (((dt * 16 + lg * 4 + 2) * 2) ^ qx)) = w1;
  }
  __syncthreads();
  if (wValid) {
    #pragma unroll
    for (int it = 0; it < 10; ++it) {
      const int flat = it * 64 + lane;
      const int q = flat / 40, c = flat - (flat / 40) * 40;
      const i32x4 v = *(const i32x4*)(ep + q * 640 + ((c * 16) ^ ((q & 7) << 4)));
      *(i32x4*)(Ob + ((size_t)cls * qRows + qt * 16 + q) * DD + c * 8) = v;
    }
  }
}

// ---------------------------------------------------------------------------
// Weight prep 1 (grid.z):
//  z=0: BtS=(Wsame)^T bf16  z=1: BtD=(Wdiff)^T bf16
//  z=2: GfT[n][k] = sum_m Wk[n,m] Wq[k,m]  (fp32; G[k,n] transposed)
//  z=3: BtVF[n][k] = sum_m Wfc[m,n] Wv[k,m]
//  z=4 (x==0): vbias, bvf, u = lng*Wout, scal = {sum lng*Wout, sum lnb*Wout+bout}
// ---------------------------------------------------------------------------
__global__ __launch_bounds__(256) void wprep(
    const float* __restrict__ Wsame, const float* __restrict__ Wdiff,
    const float* __restrict__ Wk, const float* __restrict__ Wq,
    const float* __restrict__ Wfc, const float* __restrict__ Wv,
    const float* __restrict__ bq, const float* __restrict__ bv,
    const float* __restrict__ bfc,
    const float* __restrict__ lng, const float* __restrict__ lnb,
    const float* __restrict__ Wout, const float* __restrict__ bout,
    unsigned short* __restrict__ BtS, unsigned short* __restrict__ BtD,
    float* __restrict__ GfT, unsigned short* __restrict__ BtVF,
    float* __restrict__ vbias, float* __restrict__ bvf,
    float* __restrict__ u, float* __restrict__ scal)
{
  __shared__ float Ls[64 * 68];
  const int t = threadIdx.x;
  const int z = blockIdx.z;
  if (z < 2) {                                   // transpose fp32 -> bf16^T
    const float* W = z ? Wdiff : Wsame;
    unsigned short* Wt = z ? BtD : BtS;
    const int k0 = blockIdx.x * 64, n0 = blockIdx.y * 64;
    #pragma unroll
    for (int i = 0; i < 4; ++i) {
      const int flat = t + i * 256;
      const int r = flat >> 4, c = (flat & 15) * 4;
      *(float4*)&Ls[r * 68 + c] = *(const float4*)(W + (size_t)(k0 + r) * DD + n0 + c);
    }
    __syncthreads();
    #pragma unroll
    for (int j = 0; j < 2; ++j) {
      const int flat = t + j * 256;
      const int r2 = flat >> 3, c2 = flat & 7;
      union { unsigned short e[8]; i32x4 v; } uu;
      #pragma unroll
      for (int jj = 0; jj < 8; ++jj) uu.e[jj] = f2b(Ls[(c2 * 8 + jj) * 68 + r2]);
      *(i32x4*)(Wt + (size_t)(n0 + r2) * DD + k0 + c2 * 8) = uu.v;
    }
  } else if (z < 4) {                            // weight product
    const int trL = (z == 3);
    const float* L = trL ? Wfc : Wk;
    const float* R = trL ? Wv : Wq;
    float* Lsm = Ls;                // [16][68]
    float* Rsm = Ls + 16 * 68;
    const int n0 = blockIdx.x * 64, k0 = blockIdx.y * 64;
    const int tn4 = (t & 15) * 4, tk4 = (t >> 4) * 4;
    float acc[4][4] = {};
    for (int ms = 0; ms < DD; ms += 16) {
      const int lr = t >> 4, lc = (t & 15);
      #pragma unroll
      for (int i = 0; i < 4; ++i) {
        const int nn = lc * 4 + i;
        Lsm[lr * 68 + nn] = trL ? L[(size_t)(ms + lr) * DD + n0 + nn]
                                : L[(size_t)(n0 + nn) * DD + ms + lr];
        Rsm[lr * 68 + nn] = R[(size_t)(k0 + nn) * DD + ms + lr];
      }
      __syncthreads();
      #pragma unroll
      for (int mm = 0; mm < 16; ++mm) {
        float la[4], rb[4];
        #pragma unroll
        for (int i = 0; i < 4; ++i) { la[i] = Lsm[mm * 68 + tn4 + i]; rb[i] = Rsm[mm * 68 + tk4 + i]; }
        #pragma unroll
        for (int i = 0; i < 4; ++i)
          #pragma unroll
          for (int j = 0; j < 4; ++j) acc[i][j] += la[i] * rb[j];
      }
      __syncthreads();
    }
    if (z == 2) {
      #pragma unroll
      for (int i = 0; i < 4; ++i)
        #pragma unroll
        for (int j = 0; j < 4; ++j)
          GfT[(size_t)(n0 + tn4 + i) * DD + k0 + tk4 + j] = acc[i][j];
    } else {
      #pragma unroll
      for (int i = 0; i < 4; ++i)
        #pragma unroll
        for (int j = 0; j < 4; ++j)
          BtVF[(size_t)(n0 + tn4 + i) * DD + k0 + tk4 + j] = f2b(acc[i][j]);
    }
  } else {                                       // z == 4: folded biases + LN consts
    if (blockIdx.x == 0) {
      const int n0 = blockIdx.y * 64;
      if (t < 64) {
        const int n = n0 + t;
        float a = 0.f;
        for (int m = 0; m < DD; ++m) a += Wk[(size_t)n * DD + m] * bq[m];
        vbias[n] = a;
      } else if (t < 128) {
        const int n = n0 + t - 64;
        float a = 0.f;
        for (int m = 0; m < DD; ++m) a += Wfc[(size_t)m * DD + n] * bv[m];
        bvf[n] = a + bfc[n];
      } else if (t < 192) {
        const int n = n0 + t - 128;
        u[n] = lng[n] * Wout[n];
        if (n == 0) {
          float su = 0.f, b0 = 0.f;
          for (int k = 0; k < DD; ++k) { su += lng[k] * Wout[k]; b0 += lnb[k] * Wout[k]; }
          scal[0] = su; scal[1] = b0 + bout[0];
        }
      }
    }
  }
}

// ---------------------------------------------------------------------------
// Weight prep 2 (needs GfT, vbias):
//  z=0: BtDG[n][k]=sum_j Wdiff[k][j] GfT[n][j]   z=1: BtSG (Wsame)
//  z=2: x==0 Mg[c][n]=xmean[c].GfT[n], x==1 bqg, x==2 bsg
// ---------------------------------------------------------------------------
__global__ __launch_bounds__(256) void wprep2(
    const float* __restrict__ GfT,
    const float* __restrict__ Wdiff, const float* __restrict__ Wsame,
    const float* __restrict__ Xmean,
    const float* __restrict__ bdiff, const float* __restrict__ bsame,
    const float* __restrict__ vbias,
    unsigned short* __restrict__ BtDG, unsigned short* __restrict__ BtSG,
    float* __restrict__ Mg, float* __restrict__ bqg, float* __restrict__ bsg)
{
  __shared__ float Ls[2 * 16 * 68];
  const int t = threadIdx.x;
  const int z = blockIdx.z;
  if (z < 2) {
    const float* R = z ? Wsame : Wdiff;
    unsigned short* Bt = z ? BtSG : BtDG;
    float* Lsm = Ls;
    float* Rsm = Ls + 16 * 68;
    const int n0 = blockIdx.x * 64, k0 = blockIdx.y * 64;
    const int tn4 = (t & 15) * 4, tk4 = (t >> 4) * 4;
    float acc[4][4] = {};
    for (int ms = 0; ms < DD; ms += 16) {
      const int lr = t >> 4, lc = (t & 15);
      #pragma unroll
      for (int i = 0; i < 4; ++i) {
        const int nn = lc * 4 + i;
        Lsm[lr * 68 + nn] = GfT[(size_t)(n0 + nn) * DD + ms + lr];
        Rsm[lr * 68 + nn] = R[(size_t)(k0 + nn) * DD + ms + lr];
      }
      __syncthreads();
      #pragma unroll
      for (int mm = 0; mm < 16; ++mm) {
        float la[4], rb[4];
        #pragma unroll
        for (int i = 0; i < 4; ++i) { la[i] = Lsm[mm * 68 + tn4 + i]; rb[i] = Rsm[mm * 68 + tk4 + i]; }
        #pragma unroll
        for (int i = 0; i < 4; ++i)
          #pragma unroll
          for (int j = 0; j < 4; ++j) acc[i][j] += la[i] * rb[j];
      }
      __syncthreads();
    }
    #pragma unroll
    for (int i = 0; i < 4; ++i)
      #pragma unroll
      for (int j = 0; j < 4; ++j)
        Bt[(size_t)(n0 + tn4 + i) * DD + k0 + tk4 + j] = f2b(acc[i][j]);
  } else {
    const int n0 = blockIdx.y * 64;
    if (blockIdx.x == 0) {                        // Mg chunk
      for (int idx = t; idx < 64 * 64; idx += 256) {
        const int c = idx >> 6, nn = n0 + (idx & 63);
        float a = 0.f;
        for (int k = 0; k < DD; ++k) a += Xmean[c * DD + k] * GfT[(size_t)nn * DD + k];
        Mg[c * DD + nn] = a;
      }
    } else if (blockIdx.x == 1) {                 // bqg
      if (t < 64) {
        const int nn = n0 + t;
        float a = 0.f;
        for (int k = 0; k < DD; ++k) a += bdiff[k] * GfT[(size_t)nn * DD + k];
        bqg[nn] = a + vbias[nn];
      }
    } else if (blockIdx.x == 2) {                 // bsg
      if (t < 64) {
        const int nn = n0 + t;
        float a = 0.f;
        for (int k = 0; k < DD; ++k) a += bsame[k] * GfT[(size_t)nn * DD + k];
        bsg[nn] = a + vbias[nn];
      }
    }
  }
}

// logits from virtual-F partials: logit = inv*(sUF - mu*sU) + B0
__global__ __launch_bounds__(256) void logits_k(
    const float* __restrict__ part, const float* __restrict__ scal,
    float* __restrict__ logits)
{
  const int m = blockIdx.x * 256 + threadIdx.x;
  const float* pp = part + (size_t)m * 12;
  float sF = 0.f, sF2 = 0.f, sUF = 0.f;
  #pragma unroll
  for (int s = 0; s < 4; ++s) { sF += pp[s * 3]; sF2 += pp[s * 3 + 1]; sUF += pp[s * 3 + 2]; }
  const float mu  = sF * (1.f / DD);
  const float var = sF2 * (1.f / DD) - mu * mu;
  const float inv = rsqrtf(var + LN_EPS);
  logits[m] = inv * (sUF - mu * scal[0]) + scal[1];
}

// ---------------------------------------------------------------------------
// Final: per-class softmax over logits, weighted mean of P (bf16).
// grid (CC, 5): each block handles one 64-column d-slice of one class.
// ---------------------------------------------------------------------------
__global__ __launch_bounds__(320) void final_reduce(
    const float* __restrict__ logits_s, const float* __restrict__ logits_d,
    const unsigned short* __restrict__ Ps, const unsigned short* __restrict__ Pd,
    float* __restrict__ out)
{
  const int c = blockIdx.x;
  const int dt = blockIdx.y;
  const int t = threadIdx.x;
  __shared__ float w[16 + ND];
  __shared__ float red[5];
  __shared__ float accs[5][64];
  if (t < 16) w[t] = logits_s[c * 16 + t];
  for (int j = t; j < ND; j += 320) w[16 + j] = logits_d[c * ND + j];
  __syncthreads();
  if (t == 0) {
    float mx = w[0];
    #pragma unroll
    for (int i = 1; i < 16; ++i) mx = fmaxf(mx, w[i]);
    float ssum = 0.f;
    #pragma unroll
    for (int i = 0; i < 16; ++i) { const float e = __expf(w[i] - mx); w[i] = e; ssum += e; }
    const float inv = 1.f / ssum;
    #pragma unroll
    for (int i = 0; i < 16; ++i) w[i] *= inv;
  }
  float lm = -1e30f;
  for (int j = t; j < ND; j += 320) lm = fmaxf(lm, w[16 + j]);
  #pragma unroll
  for (int off = 32; off; off >>= 1) lm = fmaxf(lm, __shfl_xor(lm, off));
  if ((t & 63) == 0) red[t >> 6] = lm;
  __syncthreads();
  const float mx = fmaxf(fmaxf(fmaxf(red[0], red[1]), fmaxf(red[2], red[3])), red[4]);
  float ls = 0.f;
  for (int j = t; j < ND; j += 320) { const float e = __expf(w[16 + j] - mx); w[16 + j] = e; ls += e; }
  #pragma unroll
  for (int off = 32; off; off >>= 1) ls += __shfl_xor(ls, off);
  __syncthreads();
  if ((t & 63) == 0) red[t >> 6] = ls;
  __syncthreads();
  const float inv = 1.f / (red[0] + red[1] + red[2] + red[3] + red[4]);
  for (int j = t; j < ND; j += 320) w[16 + j] *= inv;
  __syncthreads();
  const int col = dt * 64 + (t & 63);
  const int jg  = t >> 6;                        // 0..4
  float acc = 0.f;
  const unsigned short* Psc = Ps + (size_t)c * SHOT * DD + col;
  const unsigned short* Pdc = Pd + (size_t)c * ND * DD + col;
  if (jg == 0) {
    #pragma unroll
    for (int i = 0; i < 16; ++i) acc += w[i] * b2f(Psc[(size_t)i * DD]);
  }
  for (int j = jg; j < ND; j += 5) acc += w[16 + j] * b2f(Pdc[(size_t)j * DD]);
  accs[jg][t & 63] = acc;
  __syncthreads();
  if (t < 64)
    out[c * DD + dt * 64 + t] =
        (accs[0][t] + accs[1][t] + accs[2][t] + accs[3][t] + accs[4][t]) * (1.f / 1024.f);
}

// ---------------------------------------------------------------------------
extern "C" void kernel_launch(void* const* d_in, const int* in_sizes, int n_in,
                              void* d_out, int out_size, void* d_ws, size_t ws_size,
                              hipStream_t stream)
{
  const float* xmean = (const float*)d_in[0];
  const float* x     = (const float*)d_in[1];
  const float* Wsame = (const float*)d_in[2];
  const float* bsame = (const float*)d_in[3];
  const float* Wdiff = (const float*)d_in[4];
  const float* bdiff = (const float*)d_in[5];
  const float* Wq    = (const float*)d_in[6];
  const float* bq    = (const float*)d_in[7];
  const float* Wk    = (const float*)d_in[8];
  const float* bk    = (const float*)d_in[9];   (void)bk; // row-const in softmax
  const float* Wv    = (const float*)d_in[10];
  const float* bv    = (const float*)d_in[11];
  const float* Wfc   = (const float*)d_in[12];
  const float* bfc   = (const float*)d_in[13];
  const float* lng   = (const float*)d_in[14];
  const float* lnb   = (const float*)d_in[15];
  const float* Wout  = (const float*)d_in[16];
  const float* boutp = (const float*)d_in[17];
  float* outp = (float*)d_out;

  char* base = (char*)d_ws;
  size_t off = 0;
  auto alloc = [&](size_t bytes) { char* p = base + off; off += (bytes + 255) & ~(size_t)255; return p; };

  const size_t WB = (size_t)DD * DD * 2;
  unsigned short* BtS  = (unsigned short*)alloc(WB);
  unsigned short* BtD  = (unsigned short*)alloc(WB);
  unsigned short* BtDG = (unsigned short*)alloc(WB);
  unsigned short* BtSG = (unsigned short*)alloc(WB);
  unsigned short* BtVF = (unsigned short*)alloc(WB);
  float* GfT   = (float*)alloc((size_t)DD * DD * 4);
  float* Mg    = (float*)alloc((size_t)CC * DD * 4);
  float* vbias = (float*)alloc(DD * 4);
  float* bvf   = (float*)alloc(DD * 4);
  float* bqg   = (float*)alloc(DD * 4);
  float* bsg   = (float*)alloc(DD * 4);
  float* ubuf  = (float*)alloc(DD * 4);
  float* scal  = (float*)alloc(2 * 4);
  unsigned short* P_b  = (unsigned short*)alloc((size_t)MT * DD * 2);
  unsigned short* Qg_b = (unsigned short*)alloc((size_t)MT * DD * 2);
  unsigned short* O_b  = (unsigned short*)alloc((size_t)MT * DD * 2);
  unsigned short* PtD  = (unsigned short*)alloc((size_t)CC * DD * 1024 * 2);
  unsigned short* PtS  = (unsigned short*)alloc((size_t)CC * DD * 32 * 2);
  float* part   = (float*)alloc((size_t)MT * 12 * 4);
  float* logits = (float*)alloc((size_t)MT * 4);

  const dim3 blk(256);
  // ---- weight prep ----
  wprep<<<dim3(5, 5, 5), blk, 0, stream>>>(Wsame, Wdiff, Wk, Wq, Wfc, Wv,
                                           bq, bv, bfc, lng, lnb, Wout, boutp,
                                           BtS, BtD, GfT, BtVF, vbias, bvf, ubuf, scal);
  wprep2<<<dim3(5, 5, 3), blk, 0, stream>>>(GfT, Wdiff, Wsame, xmean, bdiff, bsame,
                                            vbias, BtDG, BtSG, Mg, bqg, bsg);

  // ---- P + Qg in ONE pass over the gathered A (+ fused P^T) ----
  gemm_pqg<<<dim3(MT / 128, 5), blk, 0, stream>>>(
      x, xmean, BtD, BtS, BtDG, BtSG, bdiff, bsame, bqg, bsg, Mg,
      P_b, Qg_b, PtD, PtS);
  // ---- attention (diff + same, one dispatch) ----
  attn16<<<dim3(1088), blk, 0, stream>>>(Qg_b, P_b, PtD, PtS, O_b);
  // ---- FC with virtual-F partials epilogue ----
  gemm_fc<<<dim3(MT / 128, 2), blk, 0, stream>>>(O_b, BtVF, bvf, P_b, ubuf, part);
  // ---- logits from partials ----
  logits_k<<<dim3(MT / 256), blk, 0, stream>>>(part, scal, logits);
  // ---- final softmax-weighted mean (parallel over 5 d-slices) ----
  final_reduce<<<dim3(CC, 5), dim3(320), 0, stream>>>(logits + MD, logits,
                                                      P_b + (size_t)MD * DD, P_b, outp);
}